// Round 1
// baseline (128.350 us; speedup 1.0000x reference)
//
#include <hip/hip_runtime.h>
#include <math.h>

// MutualInformationLoss on MI355X — round 9.
// Round-8 baseline: 108.8 us = 44 (harness ws-poison, fixed) + ~43 (K1)
// + ~21 (memset + K2 + K3 + launch gaps). This round:
//   1) K2+K3 fused into K1: per-block HW f64 atomics into pab64 (inline-asm
//      global_atomic_add_f64 — no CAS retries under 432-way contention),
//      last-block-done counter runs the MI finalization (atomic loads for
//      cross-XCD coherence). Removes 2 launches + 7.3 MB partial round-trip.
//   2) IMGB 4608->3456 B (rows 24..31 were garbage-tolerant anyway; reads
//      past row 23 land in the next image/guard — pollute only C cells >=23,
//      never read). LDS 36864->29696 -> 5 blocks/CU, launch_bounds(256,5):
//      20 waves/CU to fill the ~30% LDS-pipe bubbles seen at 16 waves.
//   3) Both images zeroed as one contiguous 6912 B span: 7 instrs vs 8.

#define NBINS   23
#define NCELLS  529
#define NBATCH  4
#define NVOX    884736
#define PBLK    432               // K1 blocks per batch: 432 * 2048 = 884736
#define TOTALB  (PBLK * NBATCH)   // 1728
#define RS      72                // image row stride in halves (144 B)
#define IMGB    (24 * RS * 2)     // 3456 B per image (24 rows: bins 0..22 + 1)
#define WREG    (2 * IMGB)        // 6912 B per wave (A + B images)
#define SMEMB   (4 * WREG + 2048) // 29696 B: guard covers row 24..31 overreads

typedef float    vf4  __attribute__((ext_vector_type(4)));
typedef _Float16 h8   __attribute__((ext_vector_type(8)));
typedef float    f16v __attribute__((ext_vector_type(16)));

#define G1 0.13533528f        // exp(-2)
#define G2 3.3546263e-4f      // exp(-8)
#define G3 1.5229979e-8f      // exp(-18)

// 7-bin window at rows i0..i0+6 via factored Gaussian (2 exp + 1 rcp):
//   w(t) = W0 * R^t * G(t), W0=exp(-968 v^2), R=exp(88 v), v = x - c_mid
__device__ __forceinline__ float window7(float x, int& i0, float* w)
{
    x = fminf(fmaxf(x, 0.0f), 1.0f);
    int ka = (int)floorf(fmaf(x, 22.0f, 0.5f));
    i0 = min(max(ka - 3, 0), 16);
    float v  = fmaf((float)(i0 + 3), -(1.0f / 22.0f), x);
    float W0 = __expf(-968.0f * v * v);
    float R  = __expf(88.0f * v);
    float Ri = __builtin_amdgcn_rcpf(R);
    float R2 = R * R,   R3 = R2 * R;
    float R2i = Ri * Ri, R3i = R2i * Ri;
    w[0] = W0 * (R3i * G3);
    w[1] = W0 * (R2i * G2);
    w[2] = W0 * (Ri  * G1);
    w[3] = W0;
    w[4] = W0 * (R   * G1);
    w[5] = W0 * (R2  * G2);
    w[6] = W0 * (R3  * G3);
    return ((w[0] + w[6]) + (w[1] + w[5])) + ((w[2] + w[4]) + w[3]);
}

// Hardware fp64 atomic add (fire-and-forget). Guaranteed global_atomic_add_f64
// on gfx90a+ — avoids any compiler CAS-loop fallback, which would retry-storm
// at 432 contenders per histogram cell.
__device__ __forceinline__ void atomic_add_f64(double* p, double v)
{
    asm volatile("global_atomic_add_f64 %0, %1, off" :: "v"(p), "v"(v) : "memory");
}

// -------- fused: Parzen + MFMA joint histogram + reduce + MI finalize --------
__global__ __launch_bounds__(256, 5)
void mi_fused(const float* __restrict__ pred,
              const float* __restrict__ targ,
              double* __restrict__ pab64,      // [NBATCH][NCELLS], pre-zeroed
              int* __restrict__ counter,       // pre-zeroed
              float* __restrict__ out)
{
    __shared__ __align__(16) char smem[SMEMB];
    __shared__ int s_last;

    const int p    = blockIdx.x;
    const int b    = blockIdx.y;
    const int wv   = threadIdx.x >> 6;
    const int lane = threadIdx.x & 63;
    const int m    = lane & 31;               // bin row for fragment reads
    const int h    = lane >> 5;               // k-half selector

    char* wbase = smem + wv * WREG;
    _Float16* Aimg = (_Float16*)wbase;
    _Float16* Bimg = (_Float16*)(wbase + IMGB);

    const size_t base = (size_t)b * NVOX + (size_t)p * 2048 + (size_t)wv * 512
                      + (size_t)lane * 8;
    const vf4* __restrict__ px4 = (const vf4*)(pred + base);
    const vf4* __restrict__ py4 = (const vf4*)(targ + base);
    vf4 xa = px4[0], xb = px4[1], ya = py4[0], yb = py4[1];
    float xs[8] = {xa.x, xa.y, xa.z, xa.w, xb.x, xb.y, xb.z, xb.w};
    float ys[8] = {ya.x, ya.y, ya.z, ya.w, yb.x, yb.y, yb.z, yb.w};

    f16v acc = {};

    #pragma unroll
    for (int c = 0; c < 8; ++c) {
        // zero rows 0..23 of BOTH images in one contiguous 6912 B span.
        // Rows 24..31 are never written; reads of them (A rows / B rows >=24)
        // only pollute C rows/cols >= 23, which are never consumed.
        vf4 z = {0.f, 0.f, 0.f, 0.f};
        #pragma unroll
        for (int it = 0; it < 6; ++it)
            *(vf4*)(wbase + (it * 64 + lane) * 16) = z;
        if (lane < 48)
            *(vf4*)(wbase + (384 + lane) * 16) = z;

        int ia, ja;
        float wa[7], wb[7];
        float sa = window7(xs[c], ia, wa);
        float sb = window7(ys[c], ja, wb);
        float inv = __builtin_amdgcn_rcpf(sa * sb);   // fold both norms onto A

        #pragma unroll
        for (int t = 0; t < 7; ++t) {
            Aimg[(ia + t) * RS + lane] = (_Float16)(wa[t] * inv);  // RNE cvt
            Bimg[(ja + t) * RS + lane] = (_Float16)wb[t];
        }

        // 4 k-steps of 32x32x16 (K=16 voxels each)
        #pragma unroll
        for (int s = 0; s < 4; ++s) {
            h8 Af = *(const h8*)(Aimg + m * RS + 16 * s + 8 * h);
            h8 Bf = *(const h8*)(Bimg + m * RS + 16 * s + 8 * h);
            acc = __builtin_amdgcn_mfma_f32_32x32x16_f16(Af, Bf, acc, 0, 0, 0);
        }
    }

    // epilogue: C layout col=lane&31, row=(reg&3)+8*(reg>>2)+4*h (m74/m101)
    float* tile = (float*)wbase;               // reuse wave region
    #pragma unroll
    for (int r = 0; r < 16; ++r) {
        int row = (r & 3) + 8 * (r >> 2) + 4 * h;
        tile[row * 33 + m] = acc[r];
    }
    __syncthreads();
    double* dst = pab64 + (size_t)b * NCELLS;
    for (int c = threadIdx.x; c < NCELLS; c += 256) {
        int i = c / NBINS, j = c % NBINS;
        float s = 0.0f;
        #pragma unroll
        for (int w = 0; w < 4; ++w)
            s += ((const float*)(smem + w * WREG))[i * 33 + j];
        atomic_add_f64(&dst[c], (double)s);
    }

    // ---- last-block-done: finalize MI ----
    // __syncthreads drains vmcnt(0): all this block's atomics have completed
    // at the device-coherent point before the counter bump.
    __syncthreads();
    if (threadIdx.x == 0) {
        __threadfence();
        int old = atomicAdd(counter, 1);
        s_last = (old == TOTALB - 1);
    }
    __syncthreads();
    if (!s_last) return;

    // one block, 256 threads: marginals + MI in fp64 (ex-K3).
    // Atomic loads: device-scope coherent reads across non-coherent XCD L2s.
    double* s_pab = (double*)smem;             // 529 * 8 = 4232 B
    double* s_pa  = (double*)(smem + 4240);    // 23 * 8
    double* s_pb  = (double*)(smem + 4432);    // 23 * 8
    double* s_red = (double*)(smem + 4624);    // 4 * 8

    double total = 0.0;
    for (int bb = 0; bb < NBATCH; ++bb) {
        for (int c = threadIdx.x; c < NCELLS; c += 256)
            s_pab[c] = __hip_atomic_load(&pab64[bb * NCELLS + c],
                                         __ATOMIC_RELAXED,
                                         __HIP_MEMORY_SCOPE_AGENT)
                       * (1.0 / (double)NVOX);
        __syncthreads();
        if (threadIdx.x < NBINS) {
            const int i = threadIdx.x;
            double r = 0.0, cl = 0.0;
            for (int j = 0; j < NBINS; ++j) {
                r  += s_pab[i * NBINS + j];
                cl += s_pab[j * NBINS + i];
            }
            s_pa[i] = r; s_pb[i] = cl;
        }
        __syncthreads();
        double t = 0.0;
        for (int c = threadIdx.x; c < NCELLS; c += 256) {
            double pv   = s_pab[c];
            double papb = s_pa[c / NBINS] * s_pb[c % NBINS];
            t += pv * log((pv + 1e-7) / (papb + 1e-7) + 1e-7);
        }
        #pragma unroll
        for (int off = 32; off > 0; off >>= 1) t += __shfl_down(t, off, 64);
        if ((threadIdx.x & 63) == 0) s_red[threadIdx.x >> 6] = t;
        __syncthreads();
        if (threadIdx.x == 0) total += s_red[0] + s_red[1] + s_red[2] + s_red[3];
        __syncthreads();
    }
    if (threadIdx.x == 0) out[0] = (float)(-total * 0.25);
}

extern "C" void kernel_launch(void* const* d_in, const int* in_sizes, int n_in,
                              void* d_out, int out_size, void* d_ws, size_t ws_size,
                              hipStream_t stream)
{
    const float* pred = (const float*)d_in[0];
    const float* targ = (const float*)d_in[1];
    float* out = (float*)d_out;
    char* ws = (char*)d_ws;

    // layout: [pab64: NBATCH*NCELLS f64 = 16928 B][pad][counter: int @17024]
    double* pab64  = (double*)ws;
    int*    counter = (int*)(ws + 17024);

    (void)hipMemsetAsync(ws, 0, 17152, stream);
    mi_fused<<<dim3(PBLK, NBATCH), 256, 0, stream>>>(pred, targ, pab64, counter, out);
}

// Round 3
// 107.215 us; speedup vs baseline: 1.1971x; 1.1971x over previous
//
#include <hip/hip_runtime.h>
#include <math.h>

// MutualInformationLoss on MI355X — round 11 (round-10 resubmit; container
// infra failure, no kernel signal).
// Round-9 post-mortem: fusing the reduction into K1 via per-cell f64 atomics
// regressed (K1 43 -> ~70 us): 914K device-scope atomics onto 2116 addresses
// = 432-way same-address serialization + vmcnt-drain stalls + serial finalize
// tail. Revert to round-8's zero-contention coalesced partial stores.
// Kept from round 9 (numerically validated, absmax unchanged):
//   IMGB 4608->3456 B (24 rows), LDS 29696 B -> 5 blocks/CU, 20 waves/CU
//   to fill the ~30% LDS-pipe bubbles K1 showed at 16 waves.
// New vs round 8:
//   - K2+K3 fused: K2 keeps its 27-way-contention f64 atomics (proven cheap),
//     last-block-done counter runs the fp64 MI finalize in-place.
//   - memset launch deleted: K1 block (0,0) zeroes pab64+counter (K2 only
//     touches them after K1 completes; kernel boundary gives coherence).

#define NBINS   23
#define NCELLS  529
#define NBATCH  4
#define NVOX    884736
#define PBLK    432               // K1 blocks per batch: 432 * 2048 = 884736
#define RPB     16                // partial rows per reduce block (432/27)
#define RBLK    (PBLK / RPB)      // 27
#define RTOT    (RBLK * NBATCH)   // 108 reduce blocks total
#define RS      72                // image row stride in halves (144 B)
#define IMGB    (24 * RS * 2)     // 3456 B per image (rows 0..23)
#define WREG    (2 * IMGB)        // 6912 B per wave (A + B images)
#define SMEMB   (4 * WREG + 2048) // 29696 B: guard covers B-row 24..31 overreads

typedef float    vf4  __attribute__((ext_vector_type(4)));
typedef _Float16 h8   __attribute__((ext_vector_type(8)));
typedef float    f16v __attribute__((ext_vector_type(16)));

#define G1 0.13533528f        // exp(-2)
#define G2 3.3546263e-4f      // exp(-8)
#define G3 1.5229979e-8f      // exp(-18)

// 7-bin window at rows i0..i0+6 via factored Gaussian (2 exp + 1 rcp):
//   w(t) = W0 * R^t * G(t), W0=exp(-968 v^2), R=exp(88 v), v = x - c_mid
__device__ __forceinline__ float window7(float x, int& i0, float* w)
{
    x = fminf(fmaxf(x, 0.0f), 1.0f);
    int ka = (int)floorf(fmaf(x, 22.0f, 0.5f));
    i0 = min(max(ka - 3, 0), 16);
    float v  = fmaf((float)(i0 + 3), -(1.0f / 22.0f), x);
    float W0 = __expf(-968.0f * v * v);
    float R  = __expf(88.0f * v);
    float Ri = __builtin_amdgcn_rcpf(R);
    float R2 = R * R,   R3 = R2 * R;
    float R2i = Ri * Ri, R3i = R2i * Ri;
    w[0] = W0 * (R3i * G3);
    w[1] = W0 * (R2i * G2);
    w[2] = W0 * (Ri  * G1);
    w[3] = W0;
    w[4] = W0 * (R   * G1);
    w[5] = W0 * (R2  * G2);
    w[6] = W0 * (R3  * G3);
    return ((w[0] + w[6]) + (w[1] + w[5])) + ((w[2] + w[4]) + w[3]);
}

// ---------------- K1: fused Parzen-window + MFMA joint histogram ----------------
__global__ __launch_bounds__(256, 5)
void mi_mfma(const float* __restrict__ pred,
             const float* __restrict__ targ,
             float* __restrict__ partial,      // [NBATCH*PBLK][NCELLS]
             double* __restrict__ pab64,       // zeroed here for K2
             int* __restrict__ counter)
{
    __shared__ __align__(16) char smem[SMEMB];

    // Block (0,0) zeroes K2's accumulator + counter — replaces the memset
    // launch. K2 runs after K1 completes (stream order), so no race.
    if (blockIdx.x == 0 && blockIdx.y == 0) {
        for (int c = threadIdx.x; c < NBATCH * NCELLS; c += 256)
            pab64[c] = 0.0;
        if (threadIdx.x == 0) *counter = 0;
    }

    const int p    = blockIdx.x;
    const int b    = blockIdx.y;
    const int wv   = threadIdx.x >> 6;
    const int lane = threadIdx.x & 63;
    const int m    = lane & 31;               // bin row for fragment reads
    const int h    = lane >> 5;               // k-half selector

    char* wbase = smem + wv * WREG;
    _Float16* Aimg = (_Float16*)wbase;
    _Float16* Bimg = (_Float16*)(wbase + IMGB);

    const size_t base = (size_t)b * NVOX + (size_t)p * 2048 + (size_t)wv * 512
                      + (size_t)lane * 8;
    const vf4* __restrict__ px4 = (const vf4*)(pred + base);
    const vf4* __restrict__ py4 = (const vf4*)(targ + base);
    vf4 xa = px4[0], xb = px4[1], ya = py4[0], yb = py4[1];
    float xs[8] = {xa.x, xa.y, xa.z, xa.w, xb.x, xb.y, xb.z, xb.w};
    float ys[8] = {ya.x, ya.y, ya.z, ya.w, yb.x, yb.y, yb.z, yb.w};

    f16v acc = {};

    #pragma unroll
    for (int c = 0; c < 8; ++c) {
        // zero rows 0..23 of BOTH images in one contiguous 6912 B span.
        // Rows 24..31 are never written; reads of them only pollute C
        // rows/cols >= 23, which are never consumed (validated round 9).
        vf4 z = {0.f, 0.f, 0.f, 0.f};
        #pragma unroll
        for (int it = 0; it < 6; ++it)
            *(vf4*)(wbase + (it * 64 + lane) * 16) = z;
        if (lane < 48)
            *(vf4*)(wbase + (384 + lane) * 16) = z;

        int ia, ja;
        float wa[7], wb[7];
        float sa = window7(xs[c], ia, wa);
        float sb = window7(ys[c], ja, wb);
        float inv = __builtin_amdgcn_rcpf(sa * sb);   // fold both norms onto A

        #pragma unroll
        for (int t = 0; t < 7; ++t) {
            Aimg[(ia + t) * RS + lane] = (_Float16)(wa[t] * inv);  // RNE cvt
            Bimg[(ja + t) * RS + lane] = (_Float16)wb[t];
        }

        // 4 k-steps of 32x32x16 (K=16 voxels each)
        #pragma unroll
        for (int s = 0; s < 4; ++s) {
            h8 Af = *(const h8*)(Aimg + m * RS + 16 * s + 8 * h);
            h8 Bf = *(const h8*)(Bimg + m * RS + 16 * s + 8 * h);
            acc = __builtin_amdgcn_mfma_f32_32x32x16_f16(Af, Bf, acc, 0, 0, 0);
        }
    }

    // epilogue: C layout col=lane&31, row=(reg&3)+8*(reg>>2)+4*h (m74/m101)
    float* tile = (float*)wbase;               // reuse wave region
    #pragma unroll
    for (int r = 0; r < 16; ++r) {
        int row = (r & 3) + 8 * (r >> 2) + 4 * h;
        tile[row * 33 + m] = acc[r];
    }
    __syncthreads();
    for (int c = threadIdx.x; c < NCELLS; c += 256) {
        int i = c / NBINS, j = c % NBINS;
        float s = 0.0f;
        #pragma unroll
        for (int w = 0; w < 4; ++w)
            s += ((const float*)(smem + w * WREG))[i * 33 + j];
        partial[((size_t)(b * PBLK + p)) * NCELLS + c] = s;   // coalesced rows
    }
}

// ---- K2: coalesced fp64 reduction (27x4 blocks) + last-block MI finalize ----
__global__ __launch_bounds__(256)
void mi_reduce_final(const float* __restrict__ partial,
                     double* __restrict__ pab64,
                     int* __restrict__ counter,
                     float* __restrict__ out)
{
    __shared__ double s_pab[NCELLS];
    __shared__ double s_pa[NBINS];
    __shared__ double s_pb[NBINS];
    __shared__ double s_red[4];
    __shared__ int s_last;

    const int g = blockIdx.x;                 // 0..RBLK-1
    const int b = blockIdx.y;
    const int t = threadIdx.x;
    const float* __restrict__ src =
        partial + ((size_t)b * PBLK + (size_t)g * RPB) * NCELLS;

    double a0 = 0.0, a1 = 0.0, a2 = 0.0;
    #pragma unroll
    for (int p = 0; p < RPB; ++p) {
        const float* __restrict__ row = src + (size_t)p * NCELLS;
        a0 += (double)row[t];
        a1 += (double)row[256 + t];
        if (t < NCELLS - 512) a2 += (double)row[512 + t];
    }
    atomicAdd(&pab64[b * NCELLS + t],       a0);   // 27-way contention: cheap
    atomicAdd(&pab64[b * NCELLS + 256 + t], a1);
    if (t < NCELLS - 512) atomicAdd(&pab64[b * NCELLS + 512 + t], a2);

    // last-block-done: __syncthreads drains vmcnt (atomics committed), then
    // release fence + counter bump; last block finalizes.
    __syncthreads();
    if (t == 0) {
        __threadfence();
        s_last = (atomicAdd(counter, 1) == RTOT - 1);
    }
    __syncthreads();
    if (!s_last) return;

    // marginals + MI in fp64 (ex-K3). Atomic loads: device-scope coherent
    // reads across non-coherent XCD L2s.
    double total = 0.0;
    for (int bb = 0; bb < NBATCH; ++bb) {
        for (int c = t; c < NCELLS; c += 256)
            s_pab[c] = __hip_atomic_load(&pab64[bb * NCELLS + c],
                                         __ATOMIC_RELAXED,
                                         __HIP_MEMORY_SCOPE_AGENT)
                       * (1.0 / (double)NVOX);
        __syncthreads();
        if (t < NBINS) {
            double r = 0.0, cl = 0.0;
            for (int j = 0; j < NBINS; ++j) {
                r  += s_pab[t * NBINS + j];
                cl += s_pab[j * NBINS + t];
            }
            s_pa[t] = r; s_pb[t] = cl;
        }
        __syncthreads();
        double tt = 0.0;
        for (int c = t; c < NCELLS; c += 256) {
            double pv   = s_pab[c];
            double papb = s_pa[c / NBINS] * s_pb[c % NBINS];
            tt += pv * log((pv + 1e-7) / (papb + 1e-7) + 1e-7);
        }
        #pragma unroll
        for (int off = 32; off > 0; off >>= 1) tt += __shfl_down(tt, off, 64);
        if ((t & 63) == 0) s_red[t >> 6] = tt;
        __syncthreads();
        if (t == 0) total += s_red[0] + s_red[1] + s_red[2] + s_red[3];
        __syncthreads();
    }
    if (t == 0) out[0] = (float)(-total * 0.25);
}

extern "C" void kernel_launch(void* const* d_in, const int* in_sizes, int n_in,
                              void* d_out, int out_size, void* d_ws, size_t ws_size,
                              hipStream_t stream)
{
    const float* pred = (const float*)d_in[0];
    const float* targ = (const float*)d_in[1];
    float* out = (float*)d_out;
    char* ws = (char*)d_ws;

    // layout: [partial: NBATCH*PBLK*NCELLS f32 = 3.66 MB][pab64: 2116 f64][cnt]
    const size_t off_pab64 =
        ((size_t)NBATCH * PBLK * NCELLS * 4 + 255) & ~(size_t)255;

    float*  partial = (float*)ws;
    double* pab64   = (double*)(ws + off_pab64);
    int*    counter = (int*)(ws + off_pab64 + NBATCH * NCELLS * sizeof(double));

    mi_mfma<<<dim3(PBLK, NBATCH), 256, 0, stream>>>(pred, targ, partial,
                                                    pab64, counter);
    mi_reduce_final<<<dim3(RBLK, NBATCH), 256, 0, stream>>>(partial, pab64,
                                                            counter, out);
}